// Round 6
// baseline (264.237 us; speedup 1.0000x reference)
//
#include <hip/hip_runtime.h>
#include <hip/hip_fp16.h>
#include <math.h>

#define N_ 50000
#define E_ 640000
#define H_ 128
#define L_ 3
#define G_ 256
#define C_ 10
#define NEG_SLOPE 0.2f

#define SCAN_B 256
#define NBLK ((N_ + SCAN_B - 1) / SCAN_B)   // 196

typedef _Float16 half8 __attribute__((ext_vector_type(8)));
typedef float f32x4 __attribute__((ext_vector_type(4)));

__device__ __forceinline__ float leaky(float x) { return x > 0.f ? x : NEG_SLOPE * x; }

// ---------------- utility ----------------
__global__ void zero_i32(int* __restrict__ p, int n) {
    int i = blockIdx.x * blockDim.x + threadIdx.x;
    if (i < n) p[i] = 0;
}

// ---------------- CSR build ----------------
__global__ void count_deg(const int* __restrict__ dst, int* __restrict__ cnt) {
    int i = blockIdx.x * blockDim.x + threadIdx.x;
    if (i < E_) atomicAdd(&cnt[dst[i]], 1);
}

__global__ __launch_bounds__(SCAN_B) void scan_block(const int* __restrict__ cnt,
                                                     int* __restrict__ rowptr,
                                                     int* __restrict__ bsums) {
    int tid = threadIdx.x;
    int gid = blockIdx.x * SCAN_B + tid;
    int v = (gid < N_) ? cnt[gid] : 0;
    int lane = tid & 63, wid = tid >> 6;
    int x = v;
#pragma unroll
    for (int o = 1; o < 64; o <<= 1) {
        int t = __shfl_up(x, o);
        if (lane >= o) x += t;
    }
    __shared__ int wsum[4];
    if (lane == 63) wsum[wid] = x;
    __syncthreads();
    int woff = 0;
    for (int i = 0; i < wid; i++) woff += wsum[i];
    int incl = x + woff;
    if (gid < N_) rowptr[gid] = incl - v;            // exclusive within block
    if (tid == SCAN_B - 1) bsums[blockIdx.x] = incl; // block total
}

__global__ __launch_bounds__(256) void scan_bsums(int* __restrict__ bsums, int nb) {
    int tid = threadIdx.x;
    int v = (tid < nb) ? bsums[tid] : 0;
    int lane = tid & 63, wid = tid >> 6;
    int x = v;
#pragma unroll
    for (int o = 1; o < 64; o <<= 1) {
        int t = __shfl_up(x, o);
        if (lane >= o) x += t;
    }
    __shared__ int wsum[4];
    if (lane == 63) wsum[wid] = x;
    __syncthreads();
    int woff = 0;
    for (int i = 0; i < wid; i++) woff += wsum[i];
    if (tid < nb) bsums[tid] = x + woff - v;         // exclusive
}

__global__ __launch_bounds__(SCAN_B) void add_offsets(int* __restrict__ rowptr,
                                                      const int* __restrict__ bsums) {
    int gid = blockIdx.x * SCAN_B + threadIdx.x;
    if (gid < N_) rowptr[gid] += bsums[blockIdx.x];
    if (gid == 0) rowptr[N_] = E_;
}

__global__ void fill_csr(const int* __restrict__ src, const int* __restrict__ dst,
                         const int* __restrict__ rowptr, int* __restrict__ cur,
                         int* __restrict__ col) {
    int i = blockIdx.x * blockDim.x + threadIdx.x;
    if (i < E_) {
        int d = dst[i];
        int p = atomicAdd(&cur[d], 1);
        col[rowptr[d] + p] = src[i];
    }
}

// ---------------- weight prep: Wt[l][144][128] fp16 ----------------
// rows 0..127: W^T; row 128: W@a_src; row 129: W@a_dst; rows 130..143: zero.
__global__ __launch_bounds__(256) void prep_weights(const float* __restrict__ Wc,
                                                    const float* __restrict__ a_src,
                                                    const float* __restrict__ a_dst,
                                                    __half* __restrict__ Wt) {
    int l = blockIdx.x;
    const float* W = Wc + l * 16384;
    __half* T = Wt + (size_t)l * 144 * 128;
    int t = threadIdx.x;
    for (int e = t; e < 16384; e += 256) {
        int k = e >> 7, n = e & 127;
        T[n * 128 + k] = __float2half(W[e]);
    }
    if (t < 128) {
        int k = t;
        const float* as = a_src + l * 128;
        const float* ad = a_dst + l * 128;
        float s = 0.f, d = 0.f;
#pragma unroll 8
        for (int n = 0; n < 128; n++) {
            float w = W[k * 128 + n];
            s += w * as[n];
            d += w * ad[n];
        }
        T[128 * 128 + k] = __float2half(s);
        T[129 * 128 + k] = __float2half(d);
    } else {
        int kk = t - 128;
        for (int r = 130; r < 144; r++) T[r * 128 + kk] = __float2half(0.f);
    }
}

// ---------------- MFMA GEMM: h16 = fp16(A @ W), es/ed fused ----------------
// block = 256 threads (4 waves), BM=64 rows, N=128(+16) cols, K=128.
// LDS XOR-swizzled (byte ^= (row&7)<<4) for conflict-free ds_read_b128.
template <bool FP16IN>
__global__ __launch_bounds__(256) void gemm_mfma(const void* __restrict__ Av,
                                                 const __half* __restrict__ Wt,
                                                 __half* __restrict__ h16,
                                                 float* __restrict__ es,
                                                 float* __restrict__ ed) {
    __shared__ __half Asw[64 * 128];    // 16 KB
    __shared__ __half Bsw[144 * 128];   // 36 KB
    int tid = threadIdx.x;
    int brow = blockIdx.x * 64;

    // --- stage A (swizzled) ---
    {
        int r = tid >> 2;             // 0..63
        int kc = (tid & 3) * 32;      // element index (32 elems per thread)
        int grow = brow + r;
        if (FP16IN) {
            const __half* Ah = (const __half*)Av;
            float4 vv[4];
            if (grow < N_) {
                const float4* p = (const float4*)(Ah + (size_t)grow * 128 + kc);
#pragma unroll
                for (int q = 0; q < 4; q++) vv[q] = p[q];
            } else {
                float4 zz = make_float4(0.f, 0.f, 0.f, 0.f);
#pragma unroll
                for (int q = 0; q < 4; q++) vv[q] = zz;
            }
#pragma unroll
            for (int q = 0; q < 4; q++) {
                int kbyte = kc * 2 + q * 16;
                int addr = r * 256 + (kbyte ^ ((r & 7) << 4));
                *(float4*)((char*)Asw + addr) = vv[q];
            }
        } else {
            const float* A = (const float*)Av;
            float v[32];
            if (grow < N_) {
                const float4* p = (const float4*)(A + (size_t)grow * 128 + kc);
#pragma unroll
                for (int q = 0; q < 8; q++) {
                    float4 f = p[q];
                    v[q * 4] = f.x; v[q * 4 + 1] = f.y; v[q * 4 + 2] = f.z; v[q * 4 + 3] = f.w;
                }
            } else {
#pragma unroll
                for (int q = 0; q < 32; q++) v[q] = 0.f;
            }
#pragma unroll
            for (int q = 0; q < 4; q++) {
                half8 h;
#pragma unroll
                for (int j = 0; j < 8; j++) h[j] = (_Float16)v[q * 8 + j];
                int kbyte = kc * 2 + q * 16;
                int addr = r * 256 + (kbyte ^ ((r & 7) << 4));
                *(half8*)((char*)Asw + addr) = h;
            }
        }
    }
    // --- stage B: linear fp16 copy, swizzled (2304 16B chunks) ---
    {
        const float4* src = (const float4*)Wt;
#pragma unroll
        for (int i = 0; i < 9; i++) {
            int c = tid + i * 256;
            int o = c * 16;
            int n = o >> 8;
            float4 val = src[c];
            int addr = n * 256 + ((o & 255) ^ ((n & 7) << 4));
            *(float4*)((char*)Bsw + addr) = val;
        }
    }
    __syncthreads();

    // --- MFMA: wave w -> rows w*16..+15, 9 n-tiles, 4 k-steps ---
    int w = tid >> 6, l = tid & 63;
    int lrow = l & 15, lk = l >> 4;
    f32x4 acc[9];
#pragma unroll
    for (int t = 0; t < 9; t++) acc[t] = (f32x4)0.f;
#pragma unroll
    for (int kk = 0; kk < 4; kk++) {
        int kbyte = kk * 64 + lk * 16;
        int arow = w * 16 + lrow;
        half8 af = *(const half8*)((const char*)Asw + arow * 256 + (kbyte ^ ((arow & 7) << 4)));
#pragma unroll
        for (int t = 0; t < 9; t++) {
            int n = t * 16 + lrow;
            half8 bf = *(const half8*)((const char*)Bsw + n * 256 + (kbyte ^ ((n & 7) << 4)));
            acc[t] = __builtin_amdgcn_mfma_f32_16x16x32_f16(af, bf, acc[t], 0, 0, 0);
        }
    }

    // --- epilogue: C[row][col], row=(lk*4+reg), col=lrow+16t ---
    int row0 = brow + w * 16 + lk * 4;
#pragma unroll
    for (int r = 0; r < 4; r++) {
        int grow = row0 + r;
        if (grow < N_) {
            __half* dst = h16 + (size_t)grow * 128 + lrow;
#pragma unroll
            for (int t = 0; t < 8; t++) dst[t * 16] = __float2half(acc[t][r]);
            if (lrow == 0) es[grow] = acc[8][r];
            else if (lrow == 1) ed[grow] = acc[8][r];
        }
    }
}

// ---------------- edge-softmax + aggregate (one wave per dst node) ----------------
// 16 lanes per edge x 4 edges per iteration; half8 (16B) gathers; fp32 accum;
// cross-lane fold via shfl_xor(16,32); fp16 output.
__global__ __launch_bounds__(256) void gat_aggregate(const __half* __restrict__ h16,
                                                     const float* __restrict__ es,
                                                     const float* __restrict__ ed,
                                                     const int* __restrict__ rowptr,
                                                     const int* __restrict__ col,
                                                     const float* __restrict__ bias,
                                                     __half* __restrict__ hout) {
    __shared__ int   lds_s[4][64];
    __shared__ float lds_w[4][64];
    int wv = threadIdx.x >> 6;
    int lane = threadIdx.x & 63;
    int node = blockIdx.x * 4 + wv;
    if (node >= N_) return;
    int beg = rowptr[node];
    int end = rowptr[node + 1];
    float edn = ed[node];
    float e_self = leaky(es[node] + edn);

    // chunk-0 edge per lane, cached in registers
    int i0 = beg + lane;
    int c0 = 0;
    float e0 = -INFINITY;
    if (i0 < end) { c0 = col[i0]; e0 = leaky(es[c0] + edn); }

    // max
    float m = e0;
    for (int i = i0 + 64; i < end; i += 64) m = fmaxf(m, leaky(es[col[i]] + edn));
#pragma unroll
    for (int o = 32; o; o >>= 1) m = fmaxf(m, __shfl_xor(m, o));
    m = fmaxf(m, e_self);

    // denom
    float w0 = (i0 < end) ? expf(e0 - m) : 0.f;
    float z = w0;
    for (int i = i0 + 64; i < end; i += 64) z += expf(leaky(es[col[i]] + edn) - m);
#pragma unroll
    for (int o = 32; o; o >>= 1) z += __shfl_xor(z, o);
    float w_self = expf(e_self - m);
    z += w_self;
    float inv = 1.0f / (z + 1e-16f);

    lds_s[wv][lane] = c0;
    lds_w[wv][lane] = w0;

    int eg = lane >> 4;      // edge group 0..3
    int fl = lane & 15;      // feature slot: features fl*8..fl*8+7
    float acc[8] = {0.f, 0.f, 0.f, 0.f, 0.f, 0.f, 0.f, 0.f};

    int nl = min(end - beg, 64);
#pragma unroll 2
    for (int j4 = 0; j4 < nl; j4 += 4) {
        int e = j4 + eg;
        if (e < nl) {
            int s = lds_s[wv][e];
            float wj = lds_w[wv][e];
            union { float4 f4; __half2 h2[4]; } u;
            u.f4 = *(const float4*)(h16 + (size_t)s * 128 + fl * 8);
#pragma unroll
            for (int q = 0; q < 4; q++) {
                float2 fv = __half22float2(u.h2[q]);
                acc[2 * q]     += wj * fv.x;
                acc[2 * q + 1] += wj * fv.y;
            }
        }
    }
    // rare: degree > 64
    for (int cb = beg + 64; cb < end; cb += 64) {
        int idx = cb + lane;
        int cs = 0; float cw = 0.f;
        if (idx < end) { cs = col[idx]; cw = expf(leaky(es[cs] + edn) - m); }
        lds_s[wv][lane] = cs;
        lds_w[wv][lane] = cw;
        int n2 = min(end - cb, 64);
        for (int j4 = 0; j4 < n2; j4 += 4) {
            int e = j4 + eg;
            if (e < n2) {
                int s = lds_s[wv][e];
                float wj = lds_w[wv][e];
                union { float4 f4; __half2 h2[4]; } u;
                u.f4 = *(const float4*)(h16 + (size_t)s * 128 + fl * 8);
#pragma unroll
                for (int q = 0; q < 4; q++) {
                    float2 fv = __half22float2(u.h2[q]);
                    acc[2 * q]     += wj * fv.x;
                    acc[2 * q + 1] += wj * fv.y;
                }
            }
        }
    }

    // fold the 4 edge groups
#pragma unroll
    for (int q = 0; q < 8; q++) {
        acc[q] += __shfl_xor(acc[q], 16);
        acc[q] += __shfl_xor(acc[q], 32);
    }

    if (eg == 0) {
        // self-loop + bias + relu, write half8 (16 lanes cover 256 B row)
        union { float4 f4; __half2 h2[4]; } su;
        su.f4 = *(const float4*)(h16 + (size_t)node * 128 + fl * 8);
        const float4* bp = (const float4*)(bias + fl * 8);
        float4 b0 = bp[0], b1 = bp[1];
        float bq[8] = {b0.x, b0.y, b0.z, b0.w, b1.x, b1.y, b1.z, b1.w};
        union { float4 f4; __half2 h2[4]; } ou;
#pragma unroll
        for (int q = 0; q < 4; q++) {
            float2 sv = __half22float2(su.h2[q]);
            float v0 = fmaxf((acc[2 * q]     + w_self * sv.x) * inv + bq[2 * q],     0.f);
            float v1 = fmaxf((acc[2 * q + 1] + w_self * sv.y) * inv + bq[2 * q + 1], 0.f);
            ou.h2[q] = __floats2half2_rn(v0, v1);
        }
        *(float4*)(hout + (size_t)node * 128 + fl * 8) = ou.f4;
    }
}

// ---------------- global max pool (fp16 input) ----------------
__device__ __forceinline__ int lower_bound_batch(const int* __restrict__ batch, int val) {
    int lo = 0, hi = N_;
    while (lo < hi) {
        int mid = (lo + hi) >> 1;
        if (batch[mid] < val) lo = mid + 1;
        else hi = mid;
    }
    return lo;
}

__global__ __launch_bounds__(512) void pool_max(const __half* __restrict__ h16,
                                                const int* __restrict__ batch,
                                                float* __restrict__ gpool) {
    int g = blockIdx.x;
    int s = lower_bound_batch(batch, g);
    int e = lower_bound_batch(batch, g + 1);
    int f = threadIdx.x & 127;
    int rg = threadIdx.x >> 7;
    float m = 0.f;  // h is post-ReLU (>=0), segments non-empty
    for (int i = s + rg; i < e; i += 4) m = fmaxf(m, __half2float(h16[(size_t)i * 128 + f]));
    __shared__ float red[4][128];
    red[rg][f] = m;
    __syncthreads();
    if (rg == 0) {
        m = fmaxf(fmaxf(red[0][f], red[1][f]), fmaxf(red[2][f], red[3][f]));
        gpool[g * 128 + f] = m;
    }
}

// ---------------- MLP head + log_softmax ----------------
__global__ __launch_bounds__(128) void head(const float* __restrict__ gpool,
                                            const float* __restrict__ W1,
                                            const float* __restrict__ b1,
                                            const float* __restrict__ W2,
                                            const float* __restrict__ b2,
                                            float* __restrict__ out) {
    int g = blockIdx.x;
    int t = threadIdx.x;
    __shared__ float gs[128], gp[128], lg[C_], lse;
    gs[t] = gpool[g * 128 + t];
    __syncthreads();
    float acc = b1[t];
#pragma unroll 8
    for (int k = 0; k < 128; k++) acc += gs[k] * W1[k * 128 + t];
    gp[t] = fmaxf(acc, 0.f);
    __syncthreads();
    if (t < C_) {
        float a2 = b2[t];
#pragma unroll 8
        for (int k = 0; k < 128; k++) a2 += gp[k] * W2[k * C_ + t];
        lg[t] = a2;
    }
    __syncthreads();
    if (t == 0) {
        float mm = lg[0];
#pragma unroll
        for (int i = 1; i < C_; i++) mm = fmaxf(mm, lg[i]);
        float ss = 0.f;
#pragma unroll
        for (int i = 0; i < C_; i++) ss += expf(lg[i] - mm);
        lse = mm + logf(ss);
    }
    __syncthreads();
    if (t < C_) out[g * C_ + t] = lg[t] - lse;
}

// ---------------- launch ----------------
extern "C" void kernel_launch(void* const* d_in, const int* in_sizes, int n_in,
                              void* d_out, int out_size, void* d_ws, size_t ws_size,
                              hipStream_t stream) {
    const float* x     = (const float*)d_in[0];
    const int*   eidx  = (const int*)d_in[1];
    const int*   batch = (const int*)d_in[2];
    const float* Wc    = (const float*)d_in[3];
    const float* a_src = (const float*)d_in[4];
    const float* a_dst = (const float*)d_in[5];
    const float* bc    = (const float*)d_in[6];
    const float* W1    = (const float*)d_in[7];
    const float* b1    = (const float*)d_in[8];
    const float* W2    = (const float*)d_in[9];
    const float* b2    = (const float*)d_in[10];
    float* out = (float*)d_out;

    const int* srcs = eidx;        // edge_index[0]
    const int* dsts = eidx + E_;   // edge_index[1]

    // workspace layout (16B-aligned segments)
    __half* hG16  = (__half*)d_ws;                    // N*128 fp16 (gemm out)
    __half* hB16  = hG16 + (size_t)N_ * 128;          // N*128 fp16 (aggregate out)
    float*  es    = (float*)(hB16 + (size_t)N_ * 128);// N
    float*  ed    = es + N_;                          // N
    float*  gpool = ed + N_;                          // G*128
    __half* Wt    = (__half*)(gpool + G_ * 128);      // 3*144*128
    int*    rowptr = (int*)(Wt + (size_t)3 * 144 * 128); // N+1
    int*    cnt   = rowptr + N_ + 1;                  // N
    int*    bsums = cnt + N_;                         // NBLK
    int*    col   = bsums + NBLK;                     // E

    // ---- weight prep + CSR build (CSR reused by all layers) ----
    prep_weights<<<L_, 256, 0, stream>>>(Wc, a_src, a_dst, Wt);
    zero_i32<<<(N_ + 1023) / 1024, 1024, 0, stream>>>(cnt, N_);
    count_deg<<<(E_ + 255) / 256, 256, 0, stream>>>(dsts, cnt);
    scan_block<<<NBLK, SCAN_B, 0, stream>>>(cnt, rowptr, bsums);
    scan_bsums<<<1, 256, 0, stream>>>(bsums, NBLK);
    add_offsets<<<NBLK, SCAN_B, 0, stream>>>(rowptr, bsums);
    zero_i32<<<(N_ + 1023) / 1024, 1024, 0, stream>>>(cnt, N_);
    fill_csr<<<(E_ + 255) / 256, 256, 0, stream>>>(srcs, dsts, rowptr, cnt, col);

    // ---- 3 GAT layers ----
    int gblk = (N_ + 63) / 64;
    int ablk = (N_ + 3) / 4;
    gemm_mfma<false><<<gblk, 256, 0, stream>>>(x, Wt, hG16, es, ed);
    gat_aggregate<<<ablk, 256, 0, stream>>>(hG16, es, ed, rowptr, col, bc, hB16);
    for (int l = 1; l < L_; ++l) {
        gemm_mfma<true><<<gblk, 256, 0, stream>>>(
            hB16, Wt + (size_t)l * 144 * 128, hG16, es, ed);
        gat_aggregate<<<ablk, 256, 0, stream>>>(hG16, es, ed, rowptr, col, bc + l * H_, hB16);
    }

    // ---- pool + head ----
    pool_max<<<G_, 512, 0, stream>>>(hB16, batch, gpool);
    head<<<G_, 128, 0, stream>>>(gpool, W1, b1, W2, b2, out);
}